// Round 5
// baseline (93.496 us; speedup 1.0000x reference)
//
#include <hip/hip_runtime.h>
#include <math.h>

#define B_    64
#define N_    512
#define SEM_  256
#define STR_  256
#define DIM_  512              // SEM+STR
#define ROWS_ (B_*N_)          // 32768

// ---- workspace layout (float offsets) ----
#define OFF_T      0           // 256x256 f32 (Wbil@Wp temp)
#define OFF_QT16   65536       // 256x256 bf16, Qt[e][d] = Q[d][e]
#define OFF_W116   98304       // 256x256 bf16, W116[o][d] = Wfz[o][d]
#define OFF_W2T    131072      // 256x256 f32, W2t[d][o] = Wfz[o][256+d]
#define OFF_V1     196608      // 256  Wfz2 @ exparam
#define OFF_C1     196864      // 256  Wp^T (Wbil+Wbil^T) bp
#define OFF_H      197120      // 256
#define OFF_C0     197376      // 1 (padded)
#define OFF_EV     197440      // 32768
#define OFF_FV     230208      // 32768
#define OFF_SUMP   262976      // 512*256 per-block partial sums
#define OFF_V2B    394048      // 64*256
#define OFF_ROW0   410432      // 64*256 pre-ReLU row-0 GEMM results

typedef __bf16 bf16x8 __attribute__((ext_vector_type(8)));
typedef float  f32x4  __attribute__((ext_vector_type(4)));

__device__ __forceinline__ ushort f2b(float x) {
    return __builtin_bit_cast(ushort, (__bf16)x);   // native v_cvt (RTNE)
}
__device__ __forceinline__ float bflo(unsigned u) {
    return __builtin_bit_cast(float, u << 16);
}
__device__ __forceinline__ float bfhi(unsigned u) {
    return __builtin_bit_cast(float, u & 0xffff0000u);
}

// ============ K0a: T = Wbil@Wp ; W116 ; W2t ; v1, h, c0 ============
__global__ __launch_bounds__(256) void k0a(
    const float* __restrict__ Wp, const float* __restrict__ bp,
    const float* __restrict__ Wbil, const float* __restrict__ Wfz,
    const float* __restrict__ exparam,
    float* __restrict__ T, ushort* __restrict__ W116, float* __restrict__ W2t,
    float* __restrict__ v1, float* __restrict__ h, float* __restrict__ c0)
{
    int t = threadIdx.x, a = blockIdx.x;
    float acc = 0.f;
    const float* wb = Wbil + a*256;
    for (int c = 0; c < 256; ++c) acc += wb[c] * Wp[c*256 + t];
    T[a*256 + t] = acc;
    W116[a*256 + t] = f2b(Wfz[a*512 + t]);
    W2t[t*256 + a] = Wfz[a*512 + 256 + t];          // transposed Wfz2
    if (a == 0) {
        float s = 0.f;
        const float* w2 = Wfz + t*512 + 256;
        for (int dd = 0; dd < 256; ++dd) s += w2[dd] * exparam[dd];
        v1[t] = s;
    }
    if (a == 1) {
        float g = 0.f, g2 = 0.f;
        for (int c = 0; c < 256; ++c) {
            g  += Wbil[t*256 + c] * bp[c];
            g2 += Wbil[c*256 + t] * bp[c];
        }
        h[t] = g + g2;
        __shared__ float red[256];
        red[t] = bp[t] * g;
        __syncthreads();
        for (int s2 = 128; s2 > 0; s2 >>= 1) {
            if (t < s2) red[t] += red[t + s2];
            __syncthreads();
        }
        if (t == 0) c0[0] = red[0];
    }
}

// ============ K0b: Qt16[e][d] = bf16((Wp^T @ T)[d][e]) ; c1 ============
__global__ __launch_bounds__(256) void k0b(
    const float* __restrict__ Wp, const float* __restrict__ T,
    const float* __restrict__ h,
    ushort* __restrict__ Qt16, float* __restrict__ c1)
{
    int t = threadIdx.x, d = blockIdx.x;
    float acc = 0.f;
    for (int a2 = 0; a2 < 256; ++a2) acc += Wp[a2*256 + d] * T[a2*256 + t];
    Qt16[t*256 + d] = f2b(acc);          // transposed store (e-major)
    __shared__ float red[256];
    red[t] = Wp[t*256 + d] * h[t];
    __syncthreads();
    for (int s2 = 128; s2 > 0; s2 >>= 1) {
        if (t < s2) red[t] += red[t + s2];
        __syncthreads();
    }
    if (t == 0) c1[d] = red[0];
}

// ============ K1: MFMA GEMM u = str@Q -> Ev, fv via diag-MFMA ============
// LDS ~51KB -> 3 blocks/CU. Barrier-free k-loop (B frags direct from L2).
__global__ __launch_bounds__(256, 3) void k_rowstats(
    const float* __restrict__ input, const ushort* __restrict__ Qt16,
    const float* __restrict__ c1, const float* __restrict__ c0,
    const float* __restrict__ Wfi, const float* __restrict__ bbil,
    const float* __restrict__ bfi, const float* __restrict__ W2t,
    float* __restrict__ Ev, float* __restrict__ fv, float* __restrict__ v2b)
{
    __shared__ __align__(16) char smem[52288];
    ushort* Ash   = (ushort*)smem;              // [64][256] bf16, XOR-swizzled
    ushort* Ush   = (ushort*)(smem + 32768);    // [64][128] bf16 swz (half of U')
    float*  sdiag = (float*)(smem + 49152);     // [64][4]
    float*  fdiag = (float*)(smem + 50176);     // [64][4]
    float*  s0sh  = (float*)(smem + 51200);     // [256]
    float*  shE0  = (float*)(smem + 52224);

    int t = threadIdx.x;
    int lane = t & 63, w = t >> 6;
    int g = lane >> 4, li = lane & 15;
    long rowbase = (long)blockIdx.x * 64;
    int b = (int)(rowbase >> 9);
    int i0 = (int)(rowbase & 511);
    const float* Ab = input + rowbase*DIM_ + SEM_;   // str half

    // stage A (str) tile: fp32 -> bf16, swizzled
#pragma unroll
    for (int q = 0; q < 16; ++q) {
        int v = t + 256*q;
        int r = v >> 6, c4 = v & 63;
        float4 a4 = *(const float4*)(Ab + (long)r*DIM_ + c4*4);
        ushort4 b4 = make_ushort4(f2b(a4.x), f2b(a4.y), f2b(a4.z), f2b(a4.w));
        *(ushort4*)&Ash[r*256 + ((c4*4) ^ ((r & 7) << 3))] = b4;
    }
    __syncthreads();

    f32x4 acc[4][4];
#pragma unroll
    for (int m = 0; m < 4; ++m)
#pragma unroll
        for (int n = 0; n < 4; ++n) acc[m][n] = (f32x4){0.f, 0.f, 0.f, 0.f};

    int xs = (li & 7) << 3;
#pragma unroll 2
    for (int k0 = 0; k0 < 256; k0 += 32) {
        bf16x8 af[4], bfr[4];
#pragma unroll
        for (int n = 0; n < 4; ++n)
            bfr[n] = *(const bf16x8*)&Qt16[(w*64 + n*16 + li)*256 + k0 + g*8];
#pragma unroll
        for (int m = 0; m < 4; ++m)
            af[m] = *(const bf16x8*)&Ash[(m*16 + li)*256 + ((k0 + g*8) ^ xs)];
#pragma unroll
        for (int m = 0; m < 4; ++m)
#pragma unroll
            for (int n = 0; n < 4; ++n)
                acc[m][n] = __builtin_amdgcn_mfma_f32_16x16x32_bf16(af[m], bfr[n], acc[m][n], 0, 0, 0);
    }

    // ---- epilogue: s = diag(U' Str^T), f = Wfi variant; U' in halved LDS ----
    float c1v[4];
#pragma unroll
    for (int n = 0; n < 4; ++n) c1v[n] = c1[w*64 + n*16 + li];

    f32x4 dacc[4], facc[4];
#pragma unroll
    for (int m = 0; m < 4; ++m) { dacc[m] = (f32x4){0.f,0.f,0.f,0.f}; facc[m] = (f32x4){0.f,0.f,0.f,0.f}; }

#pragma unroll
    for (int h = 0; h < 2; ++h) {
        if ((w >> 1) == h) {
            int cl0 = (w & 1)*64;
#pragma unroll
            for (int m = 0; m < 4; ++m)
#pragma unroll
                for (int n = 0; n < 4; ++n)
#pragma unroll
                    for (int reg = 0; reg < 4; ++reg) {
                        int row = m*16 + g*4 + reg;
                        int cl = cl0 + n*16 + li;
                        Ush[row*128 + (cl ^ ((row & 7) << 3))] = f2b(acc[m][n][reg] + c1v[n]);
                    }
        }
        __syncthreads();
        int kb = w*32 + g*8;           // local k in half
        int kg = h*128 + kb;           // global col
        float4 wf0 = *(const float4*)(Wfi + kg);
        float4 wf1 = *(const float4*)(Wfi + kg + 4);
        bf16x8 afw = (bf16x8){(__bf16)wf0.x, (__bf16)wf0.y, (__bf16)wf0.z, (__bf16)wf0.w,
                              (__bf16)wf1.x, (__bf16)wf1.y, (__bf16)wf1.z, (__bf16)wf1.w};
#pragma unroll
        for (int m = 0; m < 4; ++m) {
            bf16x8 afu = *(const bf16x8*)&Ush[(m*16 + li)*128 + (kb ^ xs)];
            bf16x8 bfs = *(const bf16x8*)&Ash[(m*16 + li)*256 + (kg ^ xs)];
            dacc[m] = __builtin_amdgcn_mfma_f32_16x16x32_bf16(afu, bfs, dacc[m], 0, 0, 0);
            facc[m] = __builtin_amdgcn_mfma_f32_16x16x32_bf16(afw, bfs, facc[m], 0, 0, 0);
        }
        __syncthreads();
    }

    // diag extraction: lane owns D[row=g*4+reg][col=li]; diag when li == g*4+reg
    if (g == (li >> 2)) {
        int dr = li & 3;
#pragma unroll
        for (int m = 0; m < 4; ++m) {
            float dv = dr == 0 ? dacc[m][0] : dr == 1 ? dacc[m][1] : dr == 2 ? dacc[m][2] : dacc[m][3];
            sdiag[(m*16 + li)*4 + w] = dv;
        }
    }
    if (g == 0) {
#pragma unroll
        for (int m = 0; m < 4; ++m) fdiag[(m*16 + li)*4 + w] = facc[m][0];
    }
    __syncthreads();
    if (t < 64) {
        float ss = sdiag[t*4] + sdiag[t*4+1] + sdiag[t*4+2] + sdiag[t*4+3];
        float ff = fdiag[t*4] + fdiag[t*4+1] + fdiag[t*4+2] + fdiag[t*4+3];
        float ev = expf(ss + c0[0] + bbil[0]);
        Ev[rowbase + t] = ev;
        fv[rowbase + t] = expf(ff + bfi[0]);
        if (t == 0) shE0[0] = ev;
    }

    // v2b for the block owning batch row 0
    if (i0 == 0) {
        if (t < 64)
            *(float4*)&s0sh[t*4] = *(const float4*)(input + (long)b*512*DIM_ + t*4);
        __syncthreads();
        float a2 = 0.f;
        for (int d = 0; d < 256; ++d) a2 += W2t[d*256 + t] * s0sh[d];
        v2b[b*256 + t] = shE0[0] * a2;
    }
}

// ============ K3: MFMA GEMM sem@Wfz1^T + epilogue + sump partials ============
// LDS ~41KB -> 3 blocks/CU. Barrier-free k-loop.
__global__ __launch_bounds__(256, 3) void k_final(
    const float* __restrict__ input, const ushort* __restrict__ W116,
    const float* __restrict__ v1, const float* __restrict__ v2b,
    const float* __restrict__ Ev, const float* __restrict__ fv,
    const float* __restrict__ bfz,
    float* __restrict__ sump, float* __restrict__ row0pre,
    float* __restrict__ out)
{
    __shared__ __align__(16) char smem[41792];
    ushort* Ash    = (ushort*)smem;             // [64][256] bf16 swz
    float*  Csh    = (float*)smem;              // [32][256] f32 swz (overlaps Ash)
    float*  sumred = (float*)(smem + 32768);    // [8][256]
    float*  cAs    = (float*)(smem + 40960);    // 64
    float*  cBs    = (float*)(smem + 41216);    // 64
    float*  EvL    = (float*)(smem + 41472);    // 64
    float*  wred   = (float*)(smem + 41728);    // 4

    int t = threadIdx.x;
    int lane = t & 63, w = t >> 6;
    int g = lane >> 4, li = lane & 15;
    long rowbase = (long)blockIdx.x * 64;
    int b = (int)(rowbase >> 9);
    int i0 = (int)(rowbase & 511);
    const float* Ab = input + rowbase*DIM_;          // sem half

    // Fws = sum fv over batch via wave-shuffle reduce
    float fsum = fv[b*512 + t] + fv[b*512 + 256 + t];
#pragma unroll
    for (int off = 32; off >= 1; off >>= 1) fsum += __shfl_down(fsum, off);
    if (lane == 0) wred[w] = fsum;
    __syncthreads();
    float invF = 1.0f / (wred[0] + wred[1] + wred[2] + wred[3]);

    if (t < 64) {
        int row = (int)rowbase + t;
        float fr = fv[row];
        float ev = Ev[row];
        EvL[t] = (i0 == 0 && t == 0) ? 0.f : ev;     // exclude j=0 from sump
        cAs[t] = fr * invF;                          // d0
        cBs[t] = ((i0 + t) == 0) ? -invF
               : (1.0f + (fv[b*512] - fr)*invF) / (512.0f * ev);
    }

    // stage A (sem) tile, swizzled
#pragma unroll
    for (int q = 0; q < 16; ++q) {
        int v = t + 256*q;
        int r = v >> 6, c4 = v & 63;
        float4 a4 = *(const float4*)(Ab + (long)r*DIM_ + c4*4);
        ushort4 b4 = make_ushort4(f2b(a4.x), f2b(a4.y), f2b(a4.z), f2b(a4.w));
        *(ushort4*)&Ash[r*256 + ((c4*4) ^ ((r & 7) << 3))] = b4;
    }
    __syncthreads();

    f32x4 acc[4][4];
#pragma unroll
    for (int m = 0; m < 4; ++m)
#pragma unroll
        for (int n = 0; n < 4; ++n) acc[m][n] = (f32x4){0.f, 0.f, 0.f, 0.f};

    int xs = (li & 7) << 3;
#pragma unroll 2
    for (int k0 = 0; k0 < 256; k0 += 32) {
        bf16x8 af[4], bfr[4];
#pragma unroll
        for (int n = 0; n < 4; ++n)
            bfr[n] = *(const bf16x8*)&W116[(w*64 + n*16 + li)*256 + k0 + g*8];
#pragma unroll
        for (int m = 0; m < 4; ++m)
            af[m] = *(const bf16x8*)&Ash[(m*16 + li)*256 + ((k0 + g*8) ^ xs)];
#pragma unroll
        for (int m = 0; m < 4; ++m)
#pragma unroll
            for (int n = 0; n < 4; ++n)
                acc[m][n] = __builtin_amdgcn_mfma_f32_16x16x32_bf16(af[m], bfr[n], acc[m][n], 0, 0, 0);
    }

    // ---- sump partial: sum_{j in block, j!=0} Ev_j * sem[j][d], vectorized ----
    {
        int qq = t >> 5, c8 = t & 31;
        float p[8];
#pragma unroll
        for (int i = 0; i < 8; ++i) p[i] = 0.f;
#pragma unroll
        for (int rr = 0; rr < 8; ++rr) {
            int r = qq*8 + rr;
            float ev = EvL[r];
            uint4 uv = *(const uint4*)&Ash[r*256 + ((c8*8) ^ (rr << 3))];
            p[0] += ev * bflo(uv.x); p[1] += ev * bfhi(uv.x);
            p[2] += ev * bflo(uv.y); p[3] += ev * bfhi(uv.y);
            p[4] += ev * bflo(uv.z); p[5] += ev * bfhi(uv.z);
            p[6] += ev * bflo(uv.w); p[7] += ev * bfhi(uv.w);
        }
        *(float4*)&sumred[qq*256 + c8*8]     = (float4){p[0], p[1], p[2], p[3]};
        *(float4*)&sumred[qq*256 + c8*8 + 4] = (float4){p[4], p[5], p[6], p[7]};
    }
    __syncthreads();
    {
        float sp = 0.f;
#pragma unroll
        for (int qq = 0; qq < 8; ++qq) sp += sumred[qq*256 + t];
        sump[(long)blockIdx.x*256 + t] = sp;
    }

    // epilogue vectors
    float v1v[4], v2v[4], bzv[4];
#pragma unroll
    for (int n = 0; n < 4; ++n) {
        int col = w*64 + n*16 + li;
        v1v[n] = v1[col];
        v2v[n] = v2b[b*256 + col];
        bzv[n] = bfz[col];
    }

    // two-half LDS repack; Csh stride 256, swizzle col ^ (g<<3) (g = (row_l>>2)&3)
#pragma unroll
    for (int hh = 0; hh < 2; ++hh) {
        __syncthreads();   // all Ash reads (k-loop/sump) or prior-store reads done
#pragma unroll
        for (int mm = 0; mm < 2; ++mm) {
            int m = hh*2 + mm;
#pragma unroll
            for (int reg = 0; reg < 4; ++reg) {
                int row = m*16 + g*4 + reg;
                int row_l = row - hh*32;
                int sw = ((row_l >> 2) & 3) << 3;
                float ca = cAs[row], cb = cBs[row];
                int irow = i0 + row;
#pragma unroll
                for (int n = 0; n < 4; ++n) {
                    int col = w*64 + n*16 + li;
                    float sel = (irow == 0) ? 0.f : v2v[n];
                    float val = acc[m][n][reg] + ca*v1v[n] + cb*sel + bzv[n];
                    if (irow == 0) row0pre[b*256 + col] = val;   // pre-ReLU, no v0 term
                    Csh[row_l*256 + (col ^ sw)] = fmaxf(val, 0.f);
                }
            }
        }
        __syncthreads();
#pragma unroll
        for (int q = 0; q < 8; ++q) {
            int v = t + 256*q;
            int r = v >> 6, c4 = v & 63;
            int sw = ((r >> 2) & 3) << 3;
            *(float4*)(out + (rowbase + hh*32 + r)*256 + c4*4) =
                *(const float4*)&Csh[r*256 + ((c4*4) ^ sw)];
        }
    }
}

// ============ K4: fixup row i=0 of each batch ============
__global__ __launch_bounds__(256) void k_fix(
    const float* __restrict__ sump, const float* __restrict__ fv,
    const float* __restrict__ W2t, const float* __restrict__ row0pre,
    float* __restrict__ out)
{
    int b = blockIdx.x, t = threadIdx.x;
    __shared__ float svsh[256];
    __shared__ float redF[256];
    float a = 0.f;
#pragma unroll
    for (int p = 0; p < 8; ++p) a += sump[(long)(b*8 + p)*256 + t];
    svsh[t] = a;
    redF[t] = fv[b*512 + t] + fv[b*512 + 256 + t];
    __syncthreads();
    for (int s2 = 128; s2 > 0; s2 >>= 1) {
        if (t < s2) redF[t] += redF[t + s2];
        __syncthreads();
    }
    float invF = 1.0f / redF[0];
    float a0 = 0.f;
    for (int d = 0; d < 256; ++d) a0 += W2t[d*256 + t] * svsh[d];
    out[((long)b*512)*256 + t] = fmaxf(row0pre[b*256 + t] - invF*a0, 0.f);
}

extern "C" void kernel_launch(void* const* d_in, const int* in_sizes, int n_in,
                              void* d_out, int out_size, void* d_ws, size_t ws_size,
                              hipStream_t stream) {
    const float* input   = (const float*)d_in[0];
    const float* Wp      = (const float*)d_in[1];
    const float* bp      = (const float*)d_in[2];
    const float* Wbil    = (const float*)d_in[3];
    const float* bbil    = (const float*)d_in[4];
    const float* Wfi     = (const float*)d_in[5];
    const float* bfi     = (const float*)d_in[6];
    const float* exparam = (const float*)d_in[7];
    const float* Wfz     = (const float*)d_in[8];
    const float* bfz     = (const float*)d_in[9];
    float* ws  = (float*)d_ws;
    float* out = (float*)d_out;

    float*  T     = ws + OFF_T;
    ushort* Qt16  = (ushort*)(ws + OFF_QT16);
    ushort* W116  = (ushort*)(ws + OFF_W116);
    float*  W2t   = ws + OFF_W2T;
    float*  v1    = ws + OFF_V1;
    float*  c1    = ws + OFF_C1;
    float*  h     = ws + OFF_H;
    float*  c0    = ws + OFF_C0;
    float*  Ev    = ws + OFF_EV;
    float*  fv    = ws + OFF_FV;
    float*  sump  = ws + OFF_SUMP;
    float*  v2b   = ws + OFF_V2B;
    float*  row0p = ws + OFF_ROW0;

    k0a<<<256, 256, 0, stream>>>(Wp, bp, Wbil, Wfz, exparam, T, W116, W2t, v1, h, c0);
    k0b<<<256, 256, 0, stream>>>(Wp, T, h, Qt16, c1);
    k_rowstats<<<ROWS_/64, 256, 0, stream>>>(input, Qt16, c1, c0, Wfi, bbil, bfi, W2t, Ev, fv, v2b);
    k_final<<<ROWS_/64, 256, 0, stream>>>(input, W116, v1, v2b, Ev, fv, bfz, sump, row0p, out);
    k_fix<<<B_, 256, 0, stream>>>(sump, fv, W2t, row0p, out);
}